// Round 1
// baseline (2069.247 us; speedup 1.0000x reference)
//
#include <hip/hip_runtime.h>

#define EN  512   // embed dim
#define KIN 64    // z feature dim
#define VN  2048  // vocab

// ---------------- zp = z @ pre_W + pre_b (fp32, sequential-k FMA like BLAS) ----
__global__ __launch_bounds__(256) void k_zp(const float* __restrict__ z,
                                            const float* __restrict__ W,
                                            const float* __restrict__ b,
                                            float* __restrict__ zp) {
#pragma clang fp contract(off)
  __shared__ float zs[4][KIN];
  const int tid = threadIdx.x;
  const int row0 = blockIdx.x * 4;
  const int r = tid >> 6, c = tid & 63;
  zs[r][c] = z[(size_t)(row0 + r) * KIN + c];
  __syncthreads();
  float zr[KIN];
#pragma unroll
  for (int k = 0; k < KIN; ++k) zr[k] = zs[r][k];
#pragma unroll
  for (int i = 0; i < 2; ++i) {
    const int j = 4 * (c + 64 * i);
    float4 acc = make_float4(0.f, 0.f, 0.f, 0.f);
#pragma unroll
    for (int k = 0; k < KIN; ++k) {
      const float4 w = *(const float4*)&W[(size_t)k * EN + j];
      acc.x = fmaf(zr[k], w.x, acc.x);
      acc.y = fmaf(zr[k], w.y, acc.y);
      acc.z = fmaf(zr[k], w.z, acc.z);
      acc.w = fmaf(zr[k], w.w, acc.w);
    }
    const float4 bb = *(const float4*)&b[j];
    float4 o;
    o.x = acc.x + bb.x; o.y = acc.y + bb.y;
    o.z = acc.z + bb.z; o.w = acc.w + bb.w;
    *(float4*)&zp[(size_t)(row0 + r) * EN + j] = o;
  }
}

// ---- row norms, exact numpy pairwise order: sum512 = (B0+B1)+(B2+B3),
// ---- each B = 8-accumulator unrolled sum over 128, elements are pre-rounded v*v
__global__ __launch_bounds__(256) void k_rownorm(const float* __restrict__ x,
                                                 float* __restrict__ out) {
#pragma clang fp contract(off)
  __shared__ float xs[64][129];
  const int tid = threadIdx.x;
  const int row0 = blockIdx.x * 64;
  float s[4];
  for (int ch = 0; ch < 4; ++ch) {
    __syncthreads();
#pragma unroll
    for (int i = 0; i < 32; ++i) {
      const int l = tid + i * 256;
      xs[l >> 7][l & 127] = x[(size_t)(row0 + (l >> 7)) * EN + ch * 128 + (l & 127)];
    }
    __syncthreads();
    if (tid < 64) {
      float r8[8];
#pragma unroll
      for (int j = 0; j < 8; ++j) { const float v = xs[tid][j]; r8[j] = v * v; }
      for (int i = 8; i < 128; i += 8) {
#pragma unroll
        for (int j = 0; j < 8; ++j) { const float v = xs[tid][i + j]; r8[j] = r8[j] + v * v; }
      }
      s[ch] = ((r8[0] + r8[1]) + (r8[2] + r8[3])) + ((r8[4] + r8[5]) + (r8[6] + r8[7]));
    }
  }
  if (tid < 64) out[row0 + tid] = (s[0] + s[1]) + (s[2] + s[3]);
}

// ---------------- fused distance GEMM + fp32-bucketed first-index argmin -------
#define BM 128
#define BV 128
#define BK 32
__global__ __launch_bounds__(256) void k_dist(const float* __restrict__ zp,
                                              const float* __restrict__ emb,
                                              const float* __restrict__ t1,
                                              const float* __restrict__ t2,
                                              int* __restrict__ tok,
                                              float* __restrict__ tokf) {
#pragma clang fp contract(off)
  __shared__ float As[BK][BM + 4];
  __shared__ float Bs[BK][BV + 4];
  __shared__ float rd[BM][16];
  __shared__ int   rv[BM][16];
  const int tid = threadIdx.x;
  const int row0 = blockIdx.x * BM;
  const int rg = tid & 15;   // rows 8*rg..8*rg+7
  const int cg = tid >> 4;   // cols 8*cg..8*cg+7
  float bestd[8];
  int bestv[8];
#pragma unroll
  for (int i = 0; i < 8; ++i) { bestd[i] = 3.402823466e38f; bestv[i] = 0; }
  float t1r[8];
#pragma unroll
  for (int i = 0; i < 8; ++i) t1r[i] = t1[row0 + 8 * rg + i];

  for (int chunk = 0; chunk < VN / BV; ++chunk) {
    const int v0 = chunk * BV;
    float acc[8][8];
#pragma unroll
    for (int i = 0; i < 8; ++i)
#pragma unroll
      for (int j = 0; j < 8; ++j) acc[i][j] = 0.f;

    for (int k0 = 0; k0 < EN; k0 += BK) {
      __syncthreads();
#pragma unroll
      for (int i = 0; i < 4; ++i) {             // A: 128 rows x 32 k
        const int l = tid + i * 256;
        const int m = l >> 3, kq = (l & 7) * 4;
        const float4 f = *(const float4*)&zp[(size_t)(row0 + m) * EN + k0 + kq];
        As[kq + 0][m] = f.x; As[kq + 1][m] = f.y;
        As[kq + 2][m] = f.z; As[kq + 3][m] = f.w;
      }
#pragma unroll
      for (int i = 0; i < 4; ++i) {             // B: 128 vocab x 32 k
        const int l = tid + i * 256;
        const int v = l >> 3, kq = (l & 7) * 4;
        const float4 f = *(const float4*)&emb[(size_t)(v0 + v) * EN + k0 + kq];
        Bs[kq + 0][v] = f.x; Bs[kq + 1][v] = f.y;
        Bs[kq + 2][v] = f.z; Bs[kq + 3][v] = f.w;
      }
      __syncthreads();
#pragma unroll 4
      for (int kk = 0; kk < BK; ++kk) {
        const float4 a0 = *(const float4*)&As[kk][8 * rg];
        const float4 a1 = *(const float4*)&As[kk][8 * rg + 4];
        const float4 b0 = *(const float4*)&Bs[kk][8 * cg];
        const float4 b1 = *(const float4*)&Bs[kk][8 * cg + 4];
        const float av[8] = {a0.x, a0.y, a0.z, a0.w, a1.x, a1.y, a1.z, a1.w};
        const float bv8[8] = {b0.x, b0.y, b0.z, b0.w, b1.x, b1.y, b1.z, b1.w};
#pragma unroll
        for (int i = 0; i < 8; ++i)
#pragma unroll
          for (int j = 0; j < 8; ++j) acc[i][j] = fmaf(av[i], bv8[j], acc[i][j]);
      }
    }
    // d = fl(fl(t1+t2) - 2*s); strict < keeps first (lowest v) on fp32 ties
#pragma unroll
    for (int j = 0; j < 8; ++j) {
      const int v = v0 + 8 * cg + j;
      const float t2v = t2[v];
#pragma unroll
      for (int i = 0; i < 8; ++i) {
        const float d = (t1r[i] + t2v) - 2.0f * acc[i][j];
        if (d < bestd[i]) { bestd[i] = d; bestv[i] = v; }
      }
    }
  }
  __syncthreads();
#pragma unroll
  for (int i = 0; i < 8; ++i) { rd[8 * rg + i][cg] = bestd[i]; rv[8 * rg + i][cg] = bestv[i]; }
  __syncthreads();
  if (tid < BM) {
    float m = rd[tid][0]; int mv = rv[tid][0];
#pragma unroll
    for (int c = 1; c < 16; ++c) {
      const float d = rd[tid][c]; const int v = rv[tid][c];
      if (d < m || (d == m && v < mv)) { m = d; mv = v; }
    }
    tok[row0 + tid] = mv;
    tokf[row0 + tid] = (float)mv;   // tokens written as float32 values
  }
}

// ---------------- z_q = emb[tok] @ post_W + post_b (fp32 sequential-k) ---------
__global__ __launch_bounds__(256) void k_zq(const float* __restrict__ emb,
                                            const int* __restrict__ tok,
                                            const float* __restrict__ pW,
                                            const float* __restrict__ pb,
                                            float* __restrict__ out) {
#pragma clang fp contract(off)
  __shared__ float es[64][132];
  const int tid = threadIdx.x;
  const int row0 = blockIdx.x * 64;
  const int cg = tid & 15;   // cols 4*cg..
  const int rg = tid >> 4;   // rows 4*rg..
  float acc[4][4];
#pragma unroll
  for (int r = 0; r < 4; ++r)
#pragma unroll
    for (int c = 0; c < 4; ++c) acc[r][c] = 0.f;

  for (int ch = 0; ch < 4; ++ch) {
    __syncthreads();
#pragma unroll
    for (int i = 0; i < 32; ++i) {
      const int l = tid + i * 256;
      const int rr = l >> 7, kk = l & 127;
      const int tk = tok[row0 + rr];
      es[rr][kk] = emb[(size_t)tk * EN + ch * 128 + kk];
    }
    __syncthreads();
    for (int k4 = 0; k4 < 32; ++k4) {
      const int k = 4 * k4;
      float4 w[4];
#pragma unroll
      for (int i = 0; i < 4; ++i)
        w[i] = *(const float4*)&pW[(size_t)(ch * 128 + k + i) * 64 + 4 * cg];
      float4 e[4];
#pragma unroll
      for (int r = 0; r < 4; ++r) e[r] = *(const float4*)&es[4 * rg + r][k];
#pragma unroll
      for (int r = 0; r < 4; ++r) {
        acc[r][0] = fmaf(e[r].x, w[0].x, acc[r][0]);
        acc[r][1] = fmaf(e[r].x, w[0].y, acc[r][1]);
        acc[r][2] = fmaf(e[r].x, w[0].z, acc[r][2]);
        acc[r][3] = fmaf(e[r].x, w[0].w, acc[r][3]);
        acc[r][0] = fmaf(e[r].y, w[1].x, acc[r][0]);
        acc[r][1] = fmaf(e[r].y, w[1].y, acc[r][1]);
        acc[r][2] = fmaf(e[r].y, w[1].z, acc[r][2]);
        acc[r][3] = fmaf(e[r].y, w[1].w, acc[r][3]);
        acc[r][0] = fmaf(e[r].z, w[2].x, acc[r][0]);
        acc[r][1] = fmaf(e[r].z, w[2].y, acc[r][1]);
        acc[r][2] = fmaf(e[r].z, w[2].z, acc[r][2]);
        acc[r][3] = fmaf(e[r].z, w[2].w, acc[r][3]);
        acc[r][0] = fmaf(e[r].w, w[3].x, acc[r][0]);
        acc[r][1] = fmaf(e[r].w, w[3].y, acc[r][1]);
        acc[r][2] = fmaf(e[r].w, w[3].z, acc[r][2]);
        acc[r][3] = fmaf(e[r].w, w[3].w, acc[r][3]);
      }
    }
  }
  const float4 b4 = *(const float4*)&pb[4 * cg];
#pragma unroll
  for (int r = 0; r < 4; ++r) {
    float4 o;
    o.x = acc[r][0] + b4.x; o.y = acc[r][1] + b4.y;
    o.z = acc[r][2] + b4.z; o.w = acc[r][3] + b4.w;
    *(float4*)&out[(size_t)(row0 + 4 * rg + r) * 64 + 4 * cg] = o;
  }
}

extern "C" void kernel_launch(void* const* d_in, const int* in_sizes, int n_in,
                              void* d_out, int out_size, void* d_ws, size_t ws_size,
                              hipStream_t stream) {
  const float* z     = (const float*)d_in[0];
  const float* emb   = (const float*)d_in[1];
  const float* preW  = (const float*)d_in[2];
  const float* preb  = (const float*)d_in[3];
  const float* postW = (const float*)d_in[4];
  const float* postb = (const float*)d_in[5];
  const int N = in_sizes[0] / KIN;   // 65536

  float* zp = (float*)d_ws;                    // N*512 f32
  float* t1 = zp + (size_t)N * EN;             // N
  float* t2 = t1 + N;                          // VN
  int*  tok = (int*)(t2 + VN);                 // N
  float* outf = (float*)d_out;                 // [0,N): tokens (as f32), [N,...): z_q

  k_zp     <<<N / 4,  256, 0, stream>>>(z, preW, preb, zp);
  k_rownorm<<<N / 64, 256, 0, stream>>>(zp, t1);
  k_rownorm<<<VN / 64,256, 0, stream>>>(emb, t2);
  k_dist   <<<N / BM, 256, 0, stream>>>(zp, emb, t1, t2, tok, outf);
  k_zq     <<<N / 64, 256, 0, stream>>>(emb, tok, postW, postb, outf + N);
}

// Round 2
// 1722.444 us; speedup vs baseline: 1.2013x; 1.2013x over previous
//
#include <hip/hip_runtime.h>

#define EN  512   // embed dim
#define KIN 64    // z feature dim
#define VN  2048  // vocab
#define MARGIN 4.0e-3f

typedef __attribute__((ext_vector_type(8))) short bf16x8;
typedef __attribute__((ext_vector_type(4))) float f32x4;

static __device__ inline short f2bf(float f) {
  unsigned u = __builtin_bit_cast(unsigned, f);
  unsigned r = (u + 0x7FFFu + ((u >> 16) & 1u)) >> 16;   // RNE
  return (short)r;
}

// ---------------- zp = z @ pre_W + pre_b (fp32, sequential-k FMA like BLAS) ----
__global__ __launch_bounds__(256) void k_zp(const float* __restrict__ z,
                                            const float* __restrict__ W,
                                            const float* __restrict__ b,
                                            float* __restrict__ zp) {
#pragma clang fp contract(off)
  __shared__ float zs[4][KIN];
  const int tid = threadIdx.x;
  const int row0 = blockIdx.x * 4;
  const int r = tid >> 6, c = tid & 63;
  zs[r][c] = z[(size_t)(row0 + r) * KIN + c];
  __syncthreads();
  float zr[KIN];
#pragma unroll
  for (int k = 0; k < KIN; ++k) zr[k] = zs[r][k];
#pragma unroll
  for (int i = 0; i < 2; ++i) {
    const int j = 4 * (c + 64 * i);
    float4 acc = make_float4(0.f, 0.f, 0.f, 0.f);
#pragma unroll
    for (int k = 0; k < KIN; ++k) {
      const float4 w = *(const float4*)&W[(size_t)k * EN + j];
      acc.x = fmaf(zr[k], w.x, acc.x);
      acc.y = fmaf(zr[k], w.y, acc.y);
      acc.z = fmaf(zr[k], w.z, acc.z);
      acc.w = fmaf(zr[k], w.w, acc.w);
    }
    const float4 bb = *(const float4*)&b[j];
    float4 o;
    o.x = acc.x + bb.x; o.y = acc.y + bb.y;
    o.z = acc.z + bb.z; o.w = acc.w + bb.w;
    *(float4*)&zp[(size_t)(row0 + r) * EN + j] = o;
  }
}

// ---- row norms, exact numpy pairwise order (verified R1) ----
__global__ __launch_bounds__(256) void k_rownorm(const float* __restrict__ x,
                                                 float* __restrict__ out) {
#pragma clang fp contract(off)
  __shared__ float xs[64][129];
  const int tid = threadIdx.x;
  const int row0 = blockIdx.x * 64;
  float s[4];
  for (int ch = 0; ch < 4; ++ch) {
    __syncthreads();
#pragma unroll
    for (int i = 0; i < 32; ++i) {
      const int l = tid + i * 256;
      xs[l >> 7][l & 127] = x[(size_t)(row0 + (l >> 7)) * EN + ch * 128 + (l & 127)];
    }
    __syncthreads();
    if (tid < 64) {
      float r8[8];
#pragma unroll
      for (int j = 0; j < 8; ++j) { const float v = xs[tid][j]; r8[j] = v * v; }
      for (int i = 8; i < 128; i += 8) {
#pragma unroll
        for (int j = 0; j < 8; ++j) { const float v = xs[tid][i + j]; r8[j] = r8[j] + v * v; }
      }
      s[ch] = ((r8[0] + r8[1]) + (r8[2] + r8[3])) + ((r8[4] + r8[5]) + (r8[6] + r8[7]));
    }
  }
  if (tid < 64) out[row0 + tid] = (s[0] + s[1]) + (s[2] + s[3]);
}

// ---------------- emb f32 -> bf16 ----------------
__global__ __launch_bounds__(256) void k_cvt(const float* __restrict__ src,
                                             short* __restrict__ dst) {
  const int i = blockIdx.x * 256 + threadIdx.x;   // float4 index
  const float4 f = ((const float4*)src)[i];
  short4 h;
  h.x = f2bf(f.x); h.y = f2bf(f.y); h.z = f2bf(f.z); h.w = f2bf(f.w);
  ((short4*)dst)[i] = h;
}

// ---------------- MFMA distance GEMM + candidate selection ----------------
// block: 64 rows, 4 waves = 2 m-halves x 2 n-halves.
// A (zp) staged once to LDS as bf16, XOR-swizzled, exactly 64 KB.
// B frags gathered from L2-resident emb_bf16.
__global__ __launch_bounds__(256, 2) void k_dist(const float* __restrict__ zp,
                                                 const short* __restrict__ embh,
                                                 const float* __restrict__ embf,
                                                 const float* __restrict__ t1,
                                                 const float* __restrict__ t2,
                                                 int* __restrict__ rowcnt,
                                                 unsigned short* __restrict__ slots,
                                                 unsigned long long* __restrict__ keys) {
  __shared__ short As[64 * 512];   // 64 KB, swizzled: 16B-unit col = oct ^ (row&7)
  const int tid = threadIdx.x;
  const int wave = tid >> 6, lane = tid & 63;
  const int quad = lane >> 4, l15 = lane & 15;
  const int wm = wave & 1, wn = wave >> 1;
  const int row0 = blockIdx.x * 64;

  // stage A: f32 -> bf16 -> LDS (once)
  for (int i = tid; i < 64 * 128; i += 256) {
    const int r = i >> 7, c4 = i & 127;              // c4: float4 index in row
    const float4 f = *(const float4*)&zp[(size_t)(row0 + r) * EN + 4 * c4];
    short4 h;
    h.x = f2bf(f.x); h.y = f2bf(f.y); h.z = f2bf(f.z); h.w = f2bf(f.w);
    const int oct = c4 >> 1;
    const int idx = r * 512 + ((oct ^ (r & 7)) << 3) + ((c4 & 1) << 2);
    *(short4*)&As[idx] = h;
  }
  __syncthreads();

  float rmax[2][4];
#pragma unroll
  for (int a = 0; a < 2; ++a)
#pragma unroll
    for (int r = 0; r < 4; ++r) rmax[a][r] = -3.4e38f;

  const int mrow0 = wm * 32;                          // wave's 32 rows in tile
  for (int c = 0; c < 16; ++c) {
    const int v0 = c * 128 + wn * 64;                 // wave's 64-col window
    f32x4 acc[2][4];
#pragma unroll
    for (int a = 0; a < 2; ++a)
#pragma unroll
      for (int nt = 0; nt < 4; ++nt) acc[a][nt] = (f32x4){0.f, 0.f, 0.f, 0.f};

    for (int k0 = 0; k0 < EN; k0 += 32) {
      const int oct = (k0 >> 3) + quad;
      const int m0 = mrow0 + l15;          // m-tile 0 row
      const int m1 = mrow0 + 16 + l15;     // m-tile 1 row
      const bf16x8 a0 = *(const bf16x8*)&As[m0 * 512 + ((oct ^ (m0 & 7)) << 3)];
      const bf16x8 a1 = *(const bf16x8*)&As[m1 * 512 + ((oct ^ (m1 & 7)) << 3)];
#pragma unroll
      for (int nt = 0; nt < 4; ++nt) {
        const bf16x8 bfr = *(const bf16x8*)&embh[(size_t)(v0 + nt * 16 + l15) * EN + k0 + 8 * quad];
        acc[0][nt] = __builtin_amdgcn_mfma_f32_16x16x32_bf16(a0, bfr, acc[0][nt], 0, 0, 0);
        acc[1][nt] = __builtin_amdgcn_mfma_f32_16x16x32_bf16(a1, bfr, acc[1][nt], 0, 0, 0);
      }
    }

    // g = 2*s - t2[v]; per-row running max; emit candidates
    float t2v[4];
#pragma unroll
    for (int nt = 0; nt < 4; ++nt) t2v[nt] = t2[v0 + nt * 16 + l15];
    float g[2][4][4];
#pragma unroll
    for (int a = 0; a < 2; ++a)
#pragma unroll
      for (int nt = 0; nt < 4; ++nt)
#pragma unroll
        for (int r = 0; r < 4; ++r) g[a][nt][r] = fmaf(2.f, acc[a][nt][r], -t2v[nt]);

#pragma unroll
    for (int a = 0; a < 2; ++a)
#pragma unroll
      for (int r = 0; r < 4; ++r) {
        float m = fmaxf(fmaxf(g[a][0][r], g[a][1][r]), fmaxf(g[a][2][r], g[a][3][r]));
        m = fmaxf(m, __shfl_xor(m, 1, 16));
        m = fmaxf(m, __shfl_xor(m, 2, 16));
        m = fmaxf(m, __shfl_xor(m, 4, 16));
        m = fmaxf(m, __shfl_xor(m, 8, 16));
        rmax[a][r] = fmaxf(rmax[a][r], m);
      }

#pragma unroll
    for (int a = 0; a < 2; ++a)
#pragma unroll
      for (int r = 0; r < 4; ++r) {
        const float thr = rmax[a][r] - MARGIN;
        const int grow = row0 + mrow0 + a * 16 + 4 * quad + r;
#pragma unroll
        for (int nt = 0; nt < 4; ++nt) {
          if (g[a][nt][r] > thr) {
            const int v = v0 + nt * 16 + l15;
            const int idx = atomicAdd(&rowcnt[grow], 1);
            if (idx < 32) {
              slots[grow * 32 + idx] = (unsigned short)v;
            } else {
              // overflow fallback: exact fp32 rescore inline (ultra-rare)
#pragma clang fp contract(off)
              float accx = 0.f;
              const float* zr = zp + (size_t)grow * EN;
              const float* er = embf + (size_t)v * EN;
              for (int k = 0; k < EN; ++k) accx = fmaf(zr[k], er[k], accx);
              const float d = (t1[grow] + t2[v]) - 2.0f * accx;
              unsigned u = __builtin_bit_cast(unsigned, d);
              u = (u & 0x80000000u) ? ~u : (u | 0x80000000u);
              atomicMin(keys + grow, ((unsigned long long)u << 32) | (unsigned)v);
            }
          }
        }
      }
  }
}

// ---------------- exact fp32 rescore of candidates: 1 wave per row ----------------
__global__ __launch_bounds__(256) void k_rescore(const float* __restrict__ zp,
                                                 const float* __restrict__ embf,
                                                 const float* __restrict__ t1,
                                                 const float* __restrict__ t2,
                                                 const int* __restrict__ rowcnt,
                                                 const unsigned short* __restrict__ slots,
                                                 unsigned long long* __restrict__ keys) {
#pragma clang fp contract(off)
  const int wave = threadIdx.x >> 6, lane = threadIdx.x & 63;
  const int row = blockIdx.x * 4 + wave;
  const int cnt = min(rowcnt[row], 32);
  unsigned long long key = ~0ull;
  if (lane < cnt) {
    const int v = slots[row * 32 + lane];
    const float* zr = zp + (size_t)row * EN;
    const float* er = embf + (size_t)v * EN;
    float acc = 0.f;
    for (int k = 0; k < 128; ++k) {       // sequential k=0..511, exact BLAS order
      const float4 az = ((const float4*)zr)[k];
      const float4 e = ((const float4*)er)[k];
      acc = fmaf(az.x, e.x, acc); acc = fmaf(az.y, e.y, acc);
      acc = fmaf(az.z, e.z, acc); acc = fmaf(az.w, e.w, acc);
    }
    const float d = (t1[row] + t2[v]) - 2.0f * acc;
    unsigned u = __builtin_bit_cast(unsigned, d);
    u = (u & 0x80000000u) ? ~u : (u | 0x80000000u);
    key = ((unsigned long long)u << 32) | (unsigned)v;
  }
#pragma unroll
  for (int s = 1; s < 64; s <<= 1) {
    const unsigned long long o = __shfl_xor(key, s, 64);
    key = key < o ? key : o;
  }
  if (lane == 0) atomicMin(keys + row, key);
}

// ---------------- finalize tokens ----------------
__global__ __launch_bounds__(256) void k_final(const unsigned long long* __restrict__ keys,
                                               int* __restrict__ tok,
                                               float* __restrict__ tokf) {
  const int i = blockIdx.x * 256 + threadIdx.x;
  const int v = (int)(unsigned)(keys[i] & 0xFFFFFFFFull);
  tok[i] = v;
  tokf[i] = (float)v;
}

// ---------------- z_q = emb[tok] @ post_W + post_b (fp32 sequential-k) ---------
__global__ __launch_bounds__(256) void k_zq(const float* __restrict__ emb,
                                            const int* __restrict__ tok,
                                            const float* __restrict__ pW,
                                            const float* __restrict__ pb,
                                            float* __restrict__ out) {
#pragma clang fp contract(off)
  __shared__ float es[64][132];
  const int tid = threadIdx.x;
  const int row0 = blockIdx.x * 64;
  const int cg = tid & 15;
  const int rg = tid >> 4;
  float acc[4][4];
#pragma unroll
  for (int r = 0; r < 4; ++r)
#pragma unroll
    for (int c = 0; c < 4; ++c) acc[r][c] = 0.f;

  for (int ch = 0; ch < 4; ++ch) {
    __syncthreads();
#pragma unroll
    for (int i = 0; i < 32; ++i) {
      const int l = tid + i * 256;
      const int rr = l >> 7, kk = l & 127;
      const int tk = tok[row0 + rr];
      es[rr][kk] = emb[(size_t)tk * EN + ch * 128 + kk];
    }
    __syncthreads();
    for (int k4 = 0; k4 < 32; ++k4) {
      const int k = 4 * k4;
      float4 w[4];
#pragma unroll
      for (int i = 0; i < 4; ++i)
        w[i] = *(const float4*)&pW[(size_t)(ch * 128 + k + i) * 64 + 4 * cg];
      float4 e[4];
#pragma unroll
      for (int r = 0; r < 4; ++r) e[r] = *(const float4*)&es[4 * rg + r][k];
#pragma unroll
      for (int r = 0; r < 4; ++r) {
        acc[r][0] = fmaf(e[r].x, w[0].x, acc[r][0]);
        acc[r][1] = fmaf(e[r].x, w[0].y, acc[r][1]);
        acc[r][2] = fmaf(e[r].x, w[0].z, acc[r][2]);
        acc[r][3] = fmaf(e[r].x, w[0].w, acc[r][3]);
        acc[r][0] = fmaf(e[r].y, w[1].x, acc[r][0]);
        acc[r][1] = fmaf(e[r].y, w[1].y, acc[r][1]);
        acc[r][2] = fmaf(e[r].y, w[1].z, acc[r][2]);
        acc[r][3] = fmaf(e[r].y, w[1].w, acc[r][3]);
        acc[r][0] = fmaf(e[r].z, w[2].x, acc[r][0]);
        acc[r][1] = fmaf(e[r].z, w[2].y, acc[r][1]);
        acc[r][2] = fmaf(e[r].z, w[2].z, acc[r][2]);
        acc[r][3] = fmaf(e[r].z, w[2].w, acc[r][3]);
        acc[r][0] = fmaf(e[r].w, w[3].x, acc[r][0]);
        acc[r][1] = fmaf(e[r].w, w[3].y, acc[r][1]);
        acc[r][2] = fmaf(e[r].w, w[3].z, acc[r][2]);
        acc[r][3] = fmaf(e[r].w, w[3].w, acc[r][3]);
      }
    }
  }
  const float4 b4 = *(const float4*)&pb[4 * cg];
#pragma unroll
  for (int r = 0; r < 4; ++r) {
    float4 o;
    o.x = acc[r][0] + b4.x; o.y = acc[r][1] + b4.y;
    o.z = acc[r][2] + b4.z; o.w = acc[r][3] + b4.w;
    *(float4*)&out[(size_t)(row0 + 4 * rg + r) * 64 + 4 * cg] = o;
  }
}

extern "C" void kernel_launch(void* const* d_in, const int* in_sizes, int n_in,
                              void* d_out, int out_size, void* d_ws, size_t ws_size,
                              hipStream_t stream) {
  const float* z     = (const float*)d_in[0];
  const float* emb   = (const float*)d_in[1];
  const float* preW  = (const float*)d_in[2];
  const float* preb  = (const float*)d_in[3];
  const float* postW = (const float*)d_in[4];
  const float* postb = (const float*)d_in[5];
  const int N = in_sizes[0] / KIN;   // 65536

  char* ws = (char*)d_ws;
  float* zp                  = (float*)ws;                          // 134,217,728 B
  unsigned long long* keys   = (unsigned long long*)(ws + 134217728);  // 512 KB
  float* t1                  = (float*)(ws + 134742016);            // 256 KB
  float* t2                  = (float*)(ws + 135004160);            // 8 KB
  int* tok                   = (int*)(ws + 135012352);              // 256 KB
  int* rowcnt                = (int*)(ws + 135274496);              // 256 KB
  unsigned short* slots      = (unsigned short*)(ws + 135536640);   // 4 MB
  short* embh                = (short*)(ws + 139730944);            // 2 MB -> end ~141.8 MB

  float* outf = (float*)d_out;   // [0,N): tokens as f32; [N,...): z_q

  hipMemsetAsync(rowcnt, 0, (size_t)N * 4, stream);
  hipMemsetAsync(keys, 0xFF, (size_t)N * 8, stream);

  k_zp     <<<N / 4,   256, 0, stream>>>(z, preW, preb, zp);
  k_rownorm<<<N / 64,  256, 0, stream>>>(zp, t1);
  k_rownorm<<<VN / 64, 256, 0, stream>>>(emb, t2);
  k_cvt    <<<VN * EN / 1024, 256, 0, stream>>>(emb, embh);
  k_dist   <<<N / 64,  256, 0, stream>>>(zp, embh, emb, t1, t2, rowcnt, slots, keys);
  k_rescore<<<N / 4,   256, 0, stream>>>(zp, emb, t1, t2, rowcnt, slots, keys);
  k_final  <<<N / 256, 256, 0, stream>>>(keys, tok, outf);
  k_zq     <<<N / 64,  256, 0, stream>>>(emb, tok, postW, postb, outf + N);
}